// Round 16
// baseline (80.650 us; speedup 1.0000x reference)
//
#include <hip/hip_runtime.h>

// LightConv: B=8, T=1024, H=8, S=64, K=31, C=512 (all fp32)
// out[b,t,h*S+s] = sum_k softmax_k(filters[b,t,h,:])[k] * x[b, t+k-15, h*S+s] + bias[h*S+s]
//
// R23 == R14 resubmitted (rounds 7-15 failed on GPUAcquisitionTimeout; holding
// the 5-blocks/CU candidate stable for clean attribution).
// R14: LDS diet: ws stride 36 -> 32 floats + XOR swizzle e ^= (row&7)<<2
//   (order-preserving within each 4-tap quad -> ds_read_b128 intact; reads
//   4-way -> 2-way; writes unchanged vs old layout). LDS = 32768 B exactly ->
//   5 blocks/CU (160KB), 20 waves/CU. __launch_bounds__(256,5): VGPR pool/SIMD
//   ~512 -> cap 102/wave at 5 waves, liveness ~90 -> fits, no spill.
//
// Session model: bench dur_us = kernel + ~65us fixed overhead (R3/R6 fit).
// Kernel ~15us now; HBM floor ~8us -> <=7us bench headroom left. This bounds
// acceptable risk: no sync-structure rewrites for the tail.
//
// INVARIANT (round-3 counters): x ring MUST stay 8 named v4 regs, never an
// indexed array (rule #20 scratch demotion cost 3.5x).
// Kept: 1024 blocks (16 t-tiles x 8 h x 8 b), XCD-chunked swizzle (batch b per
// XCD, 2MB x-slice L2-resident -> halo re-reads hit L2), global_load_lds x16B.

#define TDIM 1024
#define HH 8
#define SS 64
#define KK 31
#define CC 512
#define HK 248
#define TTILE 64
#define WIN 96
#define PAD 15
#define WSTRIDE 32
#define NBLK 1024

typedef float v4 __attribute__((ext_vector_type(4)));

__global__ __launch_bounds__(256, 5)
void lightconv_kernel(const float* __restrict__ xg,
                      const float* __restrict__ fg,
                      const float* __restrict__ bg,
                      float* __restrict__ og)
{
    __shared__ float xs[WIN * SS];          // 24576 B
    __shared__ float ws[TTILE * WSTRIDE];   //  8192 B -> total 32768 B = 5 blk/CU

    const int tid = threadIdx.x;

    // XCD-chunked work remap: XCD x processes work ids [x*128, (x+1)*128)
    const int wid = ((blockIdx.x & 7) << 7) | (blockIdx.x >> 3);

    const int tx = wid & 15;
    const int h  = (wid >> 4) & 7;
    const int b  = wid >> 7;                   // 0..7
    const int t0 = tx * TTILE;

    const int frow  = tid >> 2;                // softmax: 4 threads per t-row
    const int fbase = (tid & 3) * 8;

    const int sq = (tid & 15) << 2;            // compute: 4 t x 4 ch per thread
    const int tb = (tid >> 4) << 2;

    const bool interior = (tx != 0) && (tx != 15);

    // ---- stage x tile (DMA flies across filter-load + softmax) ----
    const float* xb = xg + ((size_t)b * TDIM) * CC + h * SS;
    if (interior) {
        #pragma unroll
        for (int i = 0; i < 6; ++i) {
            int f  = tid + i * 256;            // quad 0..1535
            int r  = f >> 4;                   // row 0..95
            int c4 = (f & 15) << 2;            // ch 0..60
            const float* gp = xb + (size_t)(t0 - PAD + r) * CC + c4;
            __builtin_amdgcn_global_load_lds(
                (const __attribute__((address_space(1))) void*)gp,
                (__attribute__((address_space(3))) void*)&xs[f << 2],
                16, 0, 0);
        }
    } else {
        #pragma unroll
        for (int i = 0; i < 6; ++i) {
            int f  = tid + i * 256;
            int r  = f >> 4;
            int c4 = (f & 15) << 2;
            int t  = t0 - PAD + r;
            v4 v = (v4)(0.f);
            if ((unsigned)t < (unsigned)TDIM)
                v = *reinterpret_cast<const v4*>(xb + (size_t)t * CC + c4);
            *reinterpret_cast<v4*>(&xs[f << 2]) = v;
        }
    }

    // ---- filters + softmax -> ws (XOR-swizzled: element e stored at e^((row&7)<<2)) ----
    {
        float v[8];
        const float* fp = fg + (size_t)(b * TDIM + t0 + frow) * HK + h * KK + fbase;
        #pragma unroll
        for (int j = 0; j < 8; ++j)
            v[j] = (fbase + j < KK) ? fp[j] : -1e30f;

        float m = v[0];
        #pragma unroll
        for (int j = 1; j < 8; ++j) m = fmaxf(m, v[j]);
        m = fmaxf(m, __shfl_xor(m, 1, 4));
        m = fmaxf(m, __shfl_xor(m, 2, 4));
        float s = 0.f;
        #pragma unroll
        for (int j = 0; j < 8; ++j) { v[j] = __expf(v[j] - m); s += v[j]; }
        s += __shfl_xor(s, 1, 4);
        s += __shfl_xor(s, 2, 4);
        float inv = 1.f / s;
        const int xr = (frow & 7) << 2;
        #pragma unroll
        for (int j = 0; j < 8; ++j)
            if (fbase + j < 32)
                ws[frow * WSTRIDE + ((fbase + j) ^ xr)] = v[j] * inv;  // tap 31 -> 0
    }

    v4 bias4 = *reinterpret_cast<const v4*>(bg + h * SS + sq);

    __syncthreads();   // drains DMA (vmcnt) + ws writes (lgkmcnt)

    // ---- compute: 8 NAMED v4 regs, ring rotation hand-unrolled ----
    v4 x0, x1, x2, x3, x4, x5, x6, x7;
    v4 acc0 = bias4, acc1 = bias4, acc2 = bias4, acc3 = bias4;

#define LOADX(DST, ROW) DST = *reinterpret_cast<const v4*>(&xs[(tb + (ROW)) * SS + sq])

    // swizzled ws read: row r, taps 4kq..4kq+3 live at 4*(kq ^ (r&7)) + i (16B aligned)
#define WREAD(KQ, TT) (*reinterpret_cast<const v4*>(                           \
        &ws[(tb + (TT)) * WSTRIDE + (((KQ) ^ ((tb + (TT)) & 7)) << 2)]))

    // A0..A6 hold xs rows tb+4kq .. tb+4kq+6.
    // out row tb+tt, tap k=4kq+m uses xs row tb+tt+4kq+m = A(tt+m).
#define FMA4(KQ, A0, A1, A2, A3, A4, A5, A6)                                   \
    {                                                                          \
        v4 w;                                                                  \
        w = WREAD(KQ, 0);                                                      \
        acc0 += A0 * w[0]; acc0 += A1 * w[1]; acc0 += A2 * w[2]; acc0 += A3 * w[3]; \
        w = WREAD(KQ, 1);                                                      \
        acc1 += A1 * w[0]; acc1 += A2 * w[1]; acc1 += A3 * w[2]; acc1 += A4 * w[3]; \
        w = WREAD(KQ, 2);                                                      \
        acc2 += A2 * w[0]; acc2 += A3 * w[1]; acc2 += A4 * w[2]; acc2 += A5 * w[3]; \
        w = WREAD(KQ, 3);                                                      \
        acc3 += A3 * w[0]; acc3 += A4 * w[1]; acc3 += A5 * w[2]; acc3 += A6 * w[3]; \
    }

    LOADX(x0, 0); LOADX(x1, 1); LOADX(x2, 2); LOADX(x3, 3);
    LOADX(x4, 4); LOADX(x5, 5); LOADX(x6, 6); LOADX(x7, 7);

    FMA4(0, x0, x1, x2, x3, x4, x5, x6);
    LOADX(x0,  8); LOADX(x1,  9); LOADX(x2, 10); LOADX(x3, 11);
    FMA4(1, x4, x5, x6, x7, x0, x1, x2);
    LOADX(x4, 12); LOADX(x5, 13); LOADX(x6, 14); LOADX(x7, 15);
    FMA4(2, x0, x1, x2, x3, x4, x5, x6);
    LOADX(x0, 16); LOADX(x1, 17); LOADX(x2, 18); LOADX(x3, 19);
    FMA4(3, x4, x5, x6, x7, x0, x1, x2);
    LOADX(x4, 20); LOADX(x5, 21); LOADX(x6, 22); LOADX(x7, 23);
    FMA4(4, x0, x1, x2, x3, x4, x5, x6);
    LOADX(x0, 24); LOADX(x1, 25); LOADX(x2, 26); LOADX(x3, 27);
    FMA4(5, x4, x5, x6, x7, x0, x1, x2);
    LOADX(x4, 28); LOADX(x5, 29); LOADX(x6, 30); LOADX(x7, 31);
    FMA4(6, x0, x1, x2, x3, x4, x5, x6);
    LOADX(x0, 32); LOADX(x1, 33); LOADX(x2, 34);
    FMA4(7, x4, x5, x6, x7, x0, x1, x2);

#undef LOADX
#undef WREAD
#undef FMA4

    float* ob = og + (size_t)(b * TDIM + t0 + tb) * CC + h * SS + sq;
    *reinterpret_cast<v4*>(ob + (size_t)0 * CC) = acc0;
    *reinterpret_cast<v4*>(ob + (size_t)1 * CC) = acc1;
    *reinterpret_cast<v4*>(ob + (size_t)2 * CC) = acc2;
    *reinterpret_cast<v4*>(ob + (size_t)3 * CC) = acc3;
}

extern "C" void kernel_launch(void* const* d_in, const int* in_sizes, int n_in,
                              void* d_out, int out_size, void* d_ws, size_t ws_size,
                              hipStream_t stream)
{
    const float* x    = (const float*)d_in[0];
    const float* f    = (const float*)d_in[1];
    const float* bias = (const float*)d_in[2];
    float* out        = (float*)d_out;
    lightconv_kernel<<<dim3(NBLK), 256, 0, stream>>>(x, f, bias, out);
}